// Round 3
// baseline (258.363 us; speedup 1.0000x reference)
//
#include <hip/hip_runtime.h>
#include <math.h>

#define T_DIM 11
#define HH 1024
#define WW 1024
#define HWSZ (HH*WW)
#define INTR 1022              // interior extent (1..1022 in full image)

struct FracM { float m[T_DIM][T_DIM]; };

// stencil coefficients (from LAPL / PX / PY), with /DX and /DX^2 folded in
#define LC0 0.34520446044393f        // laplacian corners
#define LC1 0.309591078922457f       // laplacian edges
#define LCC -2.619182157203629f     // laplacian center
#define PA  0.086301115118584f       // deriv corner coeff
#define PB  0.32739776970073f        // deriv edge coeff
#define INV_DX  1024.0f
#define INV_DX2 1048576.0f
#define R_COEF 0.01f

__global__ __launch_bounds__(256)
void fused_loss_kernel(const float* __restrict__ uv,   // [T,2,H,W]
                       const float* __restrict__ f1,   // [T,1,H,W]
                       const float* __restrict__ f2,   // [T,1,H,W]
                       double* __restrict__ partial,
                       FracM M)
{
    const int j = blockIdx.x * 64 + (threadIdx.x & 63);   // interior col 0..1021
    const int i = blockIdx.y * 4  + (threadIdx.x >> 6);   // interior row 0..1021

    float acc = 0.0f;

    if (i < INTR && j < INTR) {
        const int ci = i + 1, cj = j + 1;
        const int c  = ci * WW + cj;

        float u_c[T_DIM], v_c[T_DIM];

        #pragma unroll
        for (int t = 0; t < T_DIM; ++t) {
            const float* ub = uv + (size_t)(2 * t) * HWSZ;
            const float* vb = ub + HWSZ;

            const float u00 = ub[c - WW - 1], u01 = ub[c - WW], u02 = ub[c - WW + 1];
            const float u10 = ub[c - 1],      u11 = ub[c],      u12 = ub[c + 1];
            const float u20 = ub[c + WW - 1], u21 = ub[c + WW], u22 = ub[c + WW + 1];

            const float v00 = vb[c - WW - 1], v01 = vb[c - WW], v02 = vb[c - WW + 1];
            const float v10 = vb[c - 1],      v11 = vb[c],      v12 = vb[c + 1];
            const float v20 = vb[c + WW - 1], v21 = vb[c + WW], v22 = vb[c + WW + 1];

            u_c[t] = u11;
            v_c[t] = v11;

            const float lap_u = (LC0*(u00+u02+u20+u22) + LC1*(u01+u10+u12+u21) + LCC*u11) * INV_DX2;
            const float u_x   = (PA*(u02-u00) + PB*(u12-u10) + PA*(u22-u20)) * INV_DX;
            const float u_y   = (PA*(u20-u00) + PB*(u21-u01) + PA*(u22-u02)) * INV_DX;

            const float lap_v = (LC0*(v00+v02+v20+v22) + LC1*(v01+v10+v12+v21) + LCC*v11) * INV_DX2;
            const float v_x   = (PA*(v02-v00) + PB*(v12-v10) + PA*(v22-v20)) * INV_DX;
            const float v_y   = (PA*(v20-v00) + PB*(v21-v01) + PA*(v22-v02)) * INV_DX;

            float Du = 0.0f, Dv = 0.0f;
            #pragma unroll
            for (int s = 0; s <= t; ++s) {
                Du += M.m[t][s] * u_c[s];
                Dv += M.m[t][s] * v_c[s];
            }

            const float fu = Du + u11*u_x + v11*u_y - R_COEF*lap_u - f1[(size_t)t*HWSZ + c];
            const float fv = Dv + u11*v_x + v11*v_y - R_COEF*lap_v - f2[(size_t)t*HWSZ + c];

            acc += fu*fu + fv*fv;
        }
    }

    // ---- reduction: wave64 shfl -> LDS -> one fp64 atomic per block ----
    double dacc = (double)acc;
    #pragma unroll
    for (int off = 32; off > 0; off >>= 1)
        dacc += __shfl_down(dacc, off, 64);

    __shared__ double sdata[4];
    const int lane = threadIdx.x & 63;
    const int wid  = threadIdx.x >> 6;
    if (lane == 0) sdata[wid] = dacc;
    __syncthreads();
    if (threadIdx.x == 0) {
        const double tot = sdata[0] + sdata[1] + sdata[2] + sdata[3];
        atomicAdd(partial, tot);
    }
}

__global__ void finalize_kernel(const double* __restrict__ partial, float* __restrict__ out)
{
    // loss = mean(fu^2) + mean(fv^2); both means over T*1022*1022 elements
    const double n = (double)T_DIM * (double)INTR * (double)INTR;
    out[0] = (float)(partial[0] / n);
}

static FracM make_frac_matrix()
{
    const double alpha = 0.5;
    const int n = 9;                      // N_FRAC
    double w[n + 1];
    w[0] = 1.0;
    for (int jj = 1; jj <= n; ++jj)
        w[jj] = pow((double)(jj + 1), 1.0 - alpha) - pow((double)jj, 1.0 - alpha);

    double M[T_DIM][T_DIM] = {};
    for (int i = 1; i <= n + 1; ++i) {
        M[i][i] += w[0];
        M[i][0] -= w[i - 1];
        for (int k = 1; k < i; ++k)
            M[i][k] -= (w[i - k - 1] - w[i - k]);
    }
    const double scale = pow(0.1, -alpha) / tgamma(2.0 - alpha);  // DT^-a / gamma(2-a)

    FracM f;
    for (int i = 0; i < T_DIM; ++i)
        for (int jj = 0; jj < T_DIM; ++jj)
            f.m[i][jj] = (float)(M[i][jj] * scale);
    return f;
}

extern "C" void kernel_launch(void* const* d_in, const int* in_sizes, int n_in,
                              void* d_out, int out_size, void* d_ws, size_t ws_size,
                              hipStream_t stream)
{
    const float* uv = (const float*)d_in[0];   // output [T,2,H,W]
    const float* f1 = (const float*)d_in[1];   // [T,1,H,W]
    const float* f2 = (const float*)d_in[2];   // [T,1,H,W]
    float* out      = (float*)d_out;
    double* partial = (double*)d_ws;

    FracM M = make_frac_matrix();

    hipMemsetAsync(partial, 0, sizeof(double), stream);

    dim3 block(256, 1, 1);
    dim3 grid((INTR + 63) / 64, (INTR + 3) / 4, 1);
    fused_loss_kernel<<<grid, block, 0, stream>>>(uv, f1, f2, partial, M);

    finalize_kernel<<<1, 1, 0, stream>>>(partial, out);
}

// Round 4
// 237.302 us; speedup vs baseline: 1.0887x; 1.0887x over previous
//
#include <hip/hip_runtime.h>
#include <math.h>

#define T_DIM 11
#define HH 1024
#define WW 1024
#define HWSZ (HH*WW)
#define INTR 1022              // interior extent (1..1022 in full image)
#define NSTRIP 511             // 1022 interior cols / 2 per thread

struct FracM { float m[T_DIM][T_DIM]; };

// stencil coefficients (from LAPL / PX / PY), with /DX and /DX^2 folded in
#define LC0 0.34520446044393f        // laplacian corners
#define LC1 0.309591078922457f       // laplacian edges
#define LCC -2.619182157203629f      // laplacian center
#define PA  0.086301115118584f       // deriv corner coeff
#define PB  0.32739776970073f        // deriv edge coeff
#define INV_DX  1024.0f
#define INV_DX2 1048576.0f
#define R_COEF 0.01f

// fu = D + ucen*gx + vcen*gy - R*lap - f  for a 3x3 window x.. of one channel
__device__ __forceinline__ float residual(
    float x00, float x01, float x02,
    float x10, float x11, float x12,
    float x20, float x21, float x22,
    float ucen, float vcen, float D, float f)
{
    const float lap = (LC0*(x00+x02+x20+x22) + LC1*(x01+x10+x12+x21) + LCC*x11) * INV_DX2;
    const float gx  = (PA*(x02-x00) + PB*(x12-x10) + PA*(x22-x20)) * INV_DX;
    const float gy  = (PA*(x20-x00) + PB*(x21-x01) + PA*(x22-x02)) * INV_DX;
    return D + ucen*gx + vcen*gy - R_COEF*lap - f;
}

__global__ __launch_bounds__(256, 4)
void fused_loss_kernel(const float* __restrict__ uv,   // [T,2,H,W]
                       const float* __restrict__ f1,   // [T,1,H,W]
                       const float* __restrict__ f2,   // [T,1,H,W]
                       double* __restrict__ partial,
                       FracM M)
{
    // each thread: 2 horizontal pixels (one strip), consecutive lanes = consecutive strips
    const int sb = blockIdx.x * 64 + (threadIdx.x & 63);   // strip 0..510
    const int i  = blockIdx.y * 4  + (threadIdx.x >> 6);   // interior row 0..1021

    float acc = 0.0f;

    if (sb < NSTRIP && i < INTR) {
        const int ci = i + 1;
        const int j0 = 1 + 2 * sb;            // full-image col of px0 (odd)
        const int c  = ci * WW + j0;          // center index of px0; c-1 is 8B-aligned

        float uc0[T_DIM], vc0[T_DIM], uc1[T_DIM], vc1[T_DIM];

        #pragma unroll
        for (int t = 0; t < T_DIM; ++t) {
            const float* ub = uv + (size_t)(2 * t) * HWSZ;
            const float* vb = ub + HWSZ;

            // window cols j0-1 .. j0+2 as aligned float2 pairs, rows T/M/B
            const float2 uT_L = *(const float2*)(ub + c - WW - 1);
            const float2 uT_R = *(const float2*)(ub + c - WW + 1);
            const float2 uM_L = *(const float2*)(ub + c - 1);
            const float2 uM_R = *(const float2*)(ub + c + 1);
            const float2 uB_L = *(const float2*)(ub + c + WW - 1);
            const float2 uB_R = *(const float2*)(ub + c + WW + 1);

            const float2 vT_L = *(const float2*)(vb + c - WW - 1);
            const float2 vT_R = *(const float2*)(vb + c - WW + 1);
            const float2 vM_L = *(const float2*)(vb + c - 1);
            const float2 vM_R = *(const float2*)(vb + c + 1);
            const float2 vB_L = *(const float2*)(vb + c + WW - 1);
            const float2 vB_R = *(const float2*)(vb + c + WW + 1);

            const float* f1p = f1 + (size_t)t * HWSZ;
            const float* f2p = f2 + (size_t)t * HWSZ;
            const float f1a = f1p[c],     f1b = f1p[c + 1];
            const float f2a = f2p[c],     f2b = f2p[c + 1];

            // centers
            const float u11a = uM_L.y, u11b = uM_R.x;
            const float v11a = vM_L.y, v11b = vM_R.x;
            uc0[t] = u11a; uc1[t] = u11b;
            vc0[t] = v11a; vc1[t] = v11b;

            // fractional derivative (lower-triangular online matmul)
            float Du0 = 0.f, Dv0 = 0.f, Du1 = 0.f, Dv1 = 0.f;
            #pragma unroll
            for (int s = 0; s <= t; ++s) {
                const float m = M.m[t][s];
                Du0 += m * uc0[s]; Dv0 += m * vc0[s];
                Du1 += m * uc1[s]; Dv1 += m * vc1[s];
            }

            // px0: window cols (L.x, L.y, R.x)
            const float fu0 = residual(uT_L.x, uT_L.y, uT_R.x,
                                       uM_L.x, u11a,   uM_R.x,
                                       uB_L.x, uB_L.y, uB_R.x,
                                       u11a, v11a, Du0, f1a);
            const float fv0 = residual(vT_L.x, vT_L.y, vT_R.x,
                                       vM_L.x, v11a,   vM_R.x,
                                       vB_L.x, vB_L.y, vB_R.x,
                                       u11a, v11a, Dv0, f2a);
            // px1: window cols (L.y, R.x, R.y)
            const float fu1 = residual(uT_L.y, uT_R.x, uT_R.y,
                                       uM_L.y, u11b,   uM_R.y,
                                       uB_L.y, uB_R.x, uB_R.y,
                                       u11b, v11b, Du1, f1b);
            const float fv1 = residual(vT_L.y, vT_R.x, vT_R.y,
                                       vM_L.y, v11b,   vM_R.y,
                                       vB_L.y, vB_R.x, vB_R.y,
                                       u11b, v11b, Dv1, f2b);

            acc += fu0*fu0 + fv0*fv0 + fu1*fu1 + fv1*fv1;
        }
    }

    // ---- reduction: wave64 shfl -> LDS -> one fp64 atomic per block ----
    double dacc = (double)acc;
    #pragma unroll
    for (int off = 32; off > 0; off >>= 1)
        dacc += __shfl_down(dacc, off, 64);

    __shared__ double sdata[4];
    const int lane = threadIdx.x & 63;
    const int wid  = threadIdx.x >> 6;
    if (lane == 0) sdata[wid] = dacc;
    __syncthreads();
    if (threadIdx.x == 0) {
        const double tot = sdata[0] + sdata[1] + sdata[2] + sdata[3];
        atomicAdd(partial, tot);
    }
}

__global__ void finalize_kernel(const double* __restrict__ partial, float* __restrict__ out)
{
    const double n = (double)T_DIM * (double)INTR * (double)INTR;
    out[0] = (float)(partial[0] / n);
}

static FracM make_frac_matrix()
{
    const double alpha = 0.5;
    const int n = 9;                      // N_FRAC
    double w[n + 1];
    w[0] = 1.0;
    for (int jj = 1; jj <= n; ++jj)
        w[jj] = pow((double)(jj + 1), 1.0 - alpha) - pow((double)jj, 1.0 - alpha);

    double M[T_DIM][T_DIM] = {};
    for (int i = 1; i <= n + 1; ++i) {
        M[i][i] += w[0];
        M[i][0] -= w[i - 1];
        for (int k = 1; k < i; ++k)
            M[i][k] -= (w[i - k - 1] - w[i - k]);
    }
    const double scale = pow(0.1, -alpha) / tgamma(2.0 - alpha);  // DT^-a / gamma(2-a)

    FracM f;
    for (int i = 0; i < T_DIM; ++i)
        for (int jj = 0; jj < T_DIM; ++jj)
            f.m[i][jj] = (float)(M[i][jj] * scale);
    return f;
}

extern "C" void kernel_launch(void* const* d_in, const int* in_sizes, int n_in,
                              void* d_out, int out_size, void* d_ws, size_t ws_size,
                              hipStream_t stream)
{
    const float* uv = (const float*)d_in[0];   // output [T,2,H,W]
    const float* f1 = (const float*)d_in[1];   // [T,1,H,W]
    const float* f2 = (const float*)d_in[2];   // [T,1,H,W]
    float* out      = (float*)d_out;
    double* partial = (double*)d_ws;

    FracM M = make_frac_matrix();

    hipMemsetAsync(partial, 0, sizeof(double), stream);

    dim3 block(256, 1, 1);
    dim3 grid((NSTRIP + 63) / 64, (INTR + 3) / 4, 1);   // 8 x 256
    fused_loss_kernel<<<grid, block, 0, stream>>>(uv, f1, f2, partial, M);

    finalize_kernel<<<1, 1, 0, stream>>>(partial, out);
}